// Round 11
// baseline (154.111 us; speedup 1.0000x reference)
//
#include <hip/hip_runtime.h>
#include <hip/hip_bf16.h>
#include <stdint.h>

typedef unsigned short u16;
typedef unsigned int u32;
typedef __attribute__((ext_vector_type(4))) float f32x4;
typedef __attribute__((ext_vector_type(16))) float f32x16;
typedef __attribute__((ext_vector_type(8))) short bf16x8;
typedef __attribute__((ext_vector_type(4))) unsigned int u32x4;
typedef __attribute__((ext_vector_type(2))) unsigned int u32x2;

#define DEV __device__ __forceinline__

DEV u16 f2bf(float f) {
  union { float f; uint32_t u; } v; v.f = f;
  uint32_t u = v.u;
  return (u16)((u + 0x7fffu + ((u >> 16) & 1u)) >> 16);
}
DEV float bf2f(u16 h) {
  union { uint32_t u; float f; } v; v.u = ((uint32_t)h) << 16;
  return v.f;
}

DEV u32 cvtpk(float a, float b) {  // D.lo = bf16(a), D.hi = bf16(b), RNE
  u32 r;
  asm("v_cvt_pk_bf16_f32 %0, %1, %2" : "=v"(r) : "v"(a), "v"(b));
  return r;
}

// v_permlane32_swap_b32 a, b: a' = [a.lo32lanes, b.lo32lanes], b' = [a.hi, b.hi]
DEV void plswap(u32& a, u32& b) {
  asm("v_permlane32_swap_b32 %0, %1" : "+v"(a), "+v"(b));
}

DEV void gload_lds16(const u16* g, u16* l) {
  __builtin_amdgcn_global_load_lds(
      (const __attribute__((address_space(1))) void*)g,
      (__attribute__((address_space(3))) void*)l, 16, 0, 0);
}

// ---------------- prep: fp32 -> bf16 + transposed weights ----------------
__global__ __launch_bounds__(256) void prep_kernel(
    const float* __restrict__ Q, const float* __restrict__ K, const float* __restrict__ V,
    const float* __restrict__ WQ, const float* __restrict__ WK, const float* __restrict__ WV,
    const float* __restrict__ WO,
    u16* __restrict__ Qb, u16* __restrict__ Kb, u16* __restrict__ Vb,
    u16* __restrict__ Wt, u16* __restrict__ Wot) {
  const int i = blockIdx.x * 256 + threadIdx.x;  // 1,048,576 threads
#pragma unroll
  for (int it = 0; it < 3; ++it) {
    int idx = it * 1048576 + i;
    int which = idx >> 20, j = idx & 1048575;
    const float* src = which == 0 ? Q : (which == 1 ? K : V);
    u16* dst = which == 0 ? Qb : (which == 1 ? Kb : Vb);
    float4 v = ((const float4*)src)[j];
    u32x2 pk;
    pk[0] = (u32)f2bf(v.x) | ((u32)f2bf(v.y) << 16);
    pk[1] = (u32)f2bf(v.z) | ((u32)f2bf(v.w) << 16);
    *(u32x2*)(dst + (size_t)j * 4) = pk;
  }
#pragma unroll
  for (int it = 0; it < 4; ++it) {
    int idx = it * 1048576 + i;
    if (idx < 3145728) {
      int p = idx >> 20, r = idx & 1048575;
      int n = r >> 10, d = r & 1023;
      int h = n >> 6, k = n & 63;
      const float* src = p == 0 ? WQ : (p == 1 ? WK : WV);
      Wt[idx] = f2bf(src[(h * 1024 + d) * 64 + k]);
    } else {
      int j = idx - 3145728;
      int c = j >> 10, k = j & 1023;
      Wot[j] = f2bf(WO[k * 1024 + c]);
    }
  }
}

// ---------------- GEMM: C[4096][1024] = A[4096][1024] * Bt^T, z-batched ----------------
template <int OUT_BF16>
__global__ __launch_bounds__(256, 2) void gemm_kernel(const u16* __restrict__ A,
                                                      const u16* __restrict__ Bt,
                                                      void* __restrict__ Cout) {
  __shared__ __align__(16) u16 Alds[128 * 64];
  __shared__ __align__(16) u16 Blds[128 * 64];
  const size_t zo = blockIdx.z;
  A += zo * 4194304;
  Bt += zo * 1048576;
  const int tid = threadIdx.x;
  const int l = tid & 63, w = tid >> 6;
  const int wm = w >> 1, wn = w & 1;
  const int tileM = blockIdx.x * 128, tileN = blockIdx.y * 128;
  const int lr = l >> 3, lch = l & 7;

  f32x4 acc[4][4] = {};

  for (int kt = 0; kt < 16; ++kt) {
    const int k0 = kt * 64;
#pragma unroll
    for (int i = 0; i < 4; ++i) {
      int r = i * 32 + w * 8 + lr;
      int sch = lch ^ (r & 7);
      gload_lds16(A + (size_t)(tileM + r) * 1024 + k0 + sch * 8, Alds + i * 2048 + w * 512);
      gload_lds16(Bt + (size_t)(tileN + r) * 1024 + k0 + sch * 8, Blds + i * 2048 + w * 512);
    }
    __syncthreads();
    bf16x8 af[4][2], bfr[4][2];
#pragma unroll
    for (int m = 0; m < 4; ++m) {
#pragma unroll
      for (int kk = 0; kk < 2; ++kk) {
        int row = wm * 64 + m * 16 + (l & 15);
        int ch = ((l >> 4) + kk * 4) ^ (row & 7);
        af[m][kk] = *(const bf16x8*)(Alds + row * 64 + ch * 8);
        int rowb = wn * 64 + m * 16 + (l & 15);
        int chb = ((l >> 4) + kk * 4) ^ (rowb & 7);
        bfr[m][kk] = *(const bf16x8*)(Blds + rowb * 64 + chb * 8);
      }
    }
#pragma unroll
    for (int m = 0; m < 4; ++m)
#pragma unroll
      for (int n = 0; n < 4; ++n)
#pragma unroll
        for (int kk = 0; kk < 2; ++kk)
          acc[m][n] = __builtin_amdgcn_mfma_f32_16x16x32_bf16(af[m][kk], bfr[n][kk], acc[m][n], 0, 0, 0);
    __syncthreads();
  }
#pragma unroll
  for (int m = 0; m < 4; ++m) {
    int row0 = tileM + wm * 64 + m * 16 + ((l >> 4) << 2);
#pragma unroll
    for (int n = 0; n < 4; ++n) {
      int col = tileN + wn * 64 + n * 16 + (l & 15);
#pragma unroll
      for (int q = 0; q < 4; ++q) {
        if (OUT_BF16)
          ((u16*)Cout)[zo * 4194304 + (size_t)(row0 + q) * 1024 + col] = f2bf(acc[m][n][q]);
        else
          ((float*)Cout)[(size_t)(row0 + q) * 1024 + col] = acc[m][n][q];
      }
    }
  }
}

// ---------------- transpose Vi[4096][1024] -> Vt[(bh*64+dk)][2048] ----------------
__global__ __launch_bounds__(256) void transposeV_kernel(const u16* __restrict__ Vi,
                                                         u16* __restrict__ Vt) {
  __shared__ __align__(16) u16 tl[64][72];
  const int tid = threadIdx.x;
  const int st = blockIdx.x * 64;
  const int bh = blockIdx.y;
  const int b = bh >> 4, h = bh & 15;
#pragma unroll
  for (int i = 0; i < 2; ++i) {
    int idx = i * 256 + tid;
    int s = idx >> 3, ch = idx & 7;
    const u16* src = Vi + (size_t)(b * 2048 + st + s) * 1024 + h * 64 + ch * 8;
    u32x2 a = *(const u32x2*)src;
    u32x2 bb = *(const u32x2*)(src + 4);
    *(u32x2*)&tl[s][ch * 8] = a;
    *(u32x2*)&tl[s][ch * 8 + 4] = bb;
  }
  __syncthreads();
#pragma unroll
  for (int i = 0; i < 2; ++i) {
    int idx = i * 256 + tid;
    int dk = idx >> 3, ch = idx & 7;
    u32x4 outv;
    u16* tp = (u16*)&outv;
#pragma unroll
    for (int j = 0; j < 8; ++j) tp[j] = tl[ch * 8 + j][dk];
    *(u32x4*)(Vt + ((size_t)bh * 64 + dk) * 2048 + st + ch * 8) = outv;
  }
}

// ---------------- flash attention: LDS-staged K/V + in-register softmax ----------------
// r10-verified structure. This round: permlane32_swap half-swap (replaces shfl+cndmask),
// row-sum l via ones-MFMA (removes 32 VALU adds/tile), unroll-2 tile loop (addr folding).
__global__ __launch_bounds__(256, 3) void attn_kernel(const u16* __restrict__ Qi,
                                                      const u16* __restrict__ Ki,
                                                      const u16* __restrict__ Vt,
                                                      u16* __restrict__ Op,
                                                      float* __restrict__ Lp) {
  __shared__ __align__(16) u16 Kl[2][4096];
  __shared__ __align__(16) u16 Vl[2][4096];
  const int tid = threadIdx.x;
  const int l = tid & 63, w = tid >> 6;
  const int lq = l & 31, hi = l >> 5;
  const int lr = l >> 3, lch = l & 7;
  // bijective XCD chunk swizzle: 1024 blocks, XCD dd%8 gets 128 contiguous (=4 bh)
  const int dd = blockIdx.x;
  const int orig = (dd & 7) * 128 + (dd >> 3);
  const int bh = orig >> 5;
  const int rem = orig & 31;
  const int qb = rem >> 1, kvh = rem & 1;
  const int b = bh >> 4, h = bh & 15;
  const int qt = qb * 128 + w * 32;
  const int tb = kvh * 1024;

  const u16* Kbase = Ki + (size_t)b * 2048 * 1024 + h * 64;
  const u16* Vbase = Vt + (size_t)bh * 64 * 2048;

  // Q B-frags (col q = lq, k = s*16 + hi*8 + j), prescaled by log2(e)/8 (exp2 domain)
  bf16x8 qf[4];
  {
    const u16* qp = Qi + (size_t)(b * 2048 + qt + lq) * 1024 + h * 64 + hi * 8;
#pragma unroll
    for (int s = 0; s < 4; ++s) {
      u32x4 t4 = *(const u32x4*)(qp + s * 16);
      u16* tp = (u16*)&t4;
#pragma unroll
      for (int j = 0; j < 8; ++j) tp[j] = f2bf(bf2f(tp[j]) * 0.1803368867f);
      qf[s] = *(bf16x8*)&t4;
    }
  }

  // all-ones B-frag for the row-sum MFMA
  bf16x8 ones;
  {
    u32x4 ov;
    ov[0] = ov[1] = ov[2] = ov[3] = 0x3F803F80u;
    ones = *(bf16x8*)&ov;
  }

  f32x16 o0 = {}, o1 = {}, lacc = {};

  // stage tile `t` into buffer `bb`: K [64 t-rows][64 k], V^T [64 d-rows][64 t]
  auto STAGE = [&](int bb, int t) {
#pragma unroll
    for (int i = 0; i < 2; ++i) {
      int r = i * 32 + w * 8 + lr;
      int sch = lch ^ (r & 7);
      gload_lds16(Kbase + (size_t)(tb + t * 64 + r) * 1024 + sch * 8,
                  Kl[bb] + i * 2048 + w * 512);
      gload_lds16(Vbase + (size_t)r * 2048 + tb + t * 64 + sch * 8,
                  Vl[bb] + i * 2048 + w * 512);
    }
  };

  STAGE(0, 0);

#pragma unroll 2
  for (int tile = 0; tile < 16; ++tile) {
    const int cur = tile & 1;
    __syncthreads();  // compiler drains vmcnt: staged tile `cur` ready
    if (tile + 1 < 16) STAGE(cur ^ 1, tile + 1);
    const u16* kl = Kl[cur];
    const u16* vl = Vl[cur];

    // S^T = K Q^T: two 32-t halves
    f32x16 s0 = {}, s1 = {};
    __builtin_amdgcn_s_setprio(1);
#pragma unroll
    for (int s = 0; s < 4; ++s) {
      int row = lq, c = s * 2 + hi;
      bf16x8 kf = *(const bf16x8*)(kl + row * 64 + (c ^ (row & 7)) * 8);
      s0 = __builtin_amdgcn_mfma_f32_32x32x16_bf16(kf, qf[s], s0, 0, 0, 0);
    }
#pragma unroll
    for (int s = 0; s < 4; ++s) {
      int row = 32 + lq, c = s * 2 + hi;
      bf16x8 kf = *(const bf16x8*)(kl + row * 64 + (c ^ (row & 7)) * 8);
      s1 = __builtin_amdgcn_mfma_f32_32x32x16_bf16(kf, qf[s], s1, 0, 0, 0);
    }
    __builtin_amdgcn_s_setprio(0);

    // P = exp2(S); pack to bf16; half-swap via v_permlane32_swap_b32
    bf16x8 pa[4];
#pragma unroll
    for (int s4 = 0; s4 < 4; ++s4) {
      const int rb = 8 * (s4 & 1);
      float p[8];
#pragma unroll
      for (int j = 0; j < 8; ++j) {
        float sv = (s4 < 2) ? ((const float*)&s0)[rb + j] : ((const float*)&s1)[rb + j];
        p[j] = exp2f(sv);
      }
      u32 w10 = cvtpk(p[0], p[1]);
      u32 w11 = cvtpk(p[2], p[3]);
      u32 w20 = cvtpk(p[4], p[5]);
      u32 w21 = cvtpk(p[6], p[7]);
      plswap(w10, w20);  // w10 -> af0 = [w10.lo, w20.lo]; w20 -> af2 = [w10.hi, w20.hi]
      plswap(w11, w21);
      u32x4 af;
      af[0] = w10;
      af[1] = w11;
      af[2] = w20;
      af[3] = w21;
      pa[s4] = *(bf16x8*)&af;  // t-window s4*16
    }

    // O += P V ; l += P·1 (row-sum on the MFMA pipe)
    __builtin_amdgcn_s_setprio(1);
#pragma unroll
    for (int s4 = 0; s4 < 4; ++s4) {
      int rowd = lq, c = s4 * 2 + hi;
      bf16x8 vf = *(const bf16x8*)(vl + rowd * 64 + (c ^ (rowd & 7)) * 8);
      o0 = __builtin_amdgcn_mfma_f32_32x32x16_bf16(pa[s4], vf, o0, 0, 0, 0);
    }
#pragma unroll
    for (int s4 = 0; s4 < 4; ++s4) {
      int rowd = 32 + lq, c = s4 * 2 + hi;
      bf16x8 vf = *(const bf16x8*)(vl + rowd * 64 + (c ^ (rowd & 7)) * 8);
      o1 = __builtin_amdgcn_mfma_f32_32x32x16_bf16(pa[s4], vf, o1, 0, 0, 0);
    }
#pragma unroll
    for (int s4 = 0; s4 < 4; ++s4)
      lacc = __builtin_amdgcn_mfma_f32_32x32x16_bf16(pa[s4], ones, lacc, 0, 0, 0);
    __builtin_amdgcn_s_setprio(0);
  }

  // write unnormalized partials (D-layout: q(reg r) = (r&3)+8*(r>>2)+4*hi, d-col = lq)
#pragma unroll
  for (int r = 0; r < 16; ++r) {
    int qr = (r & 3) + 8 * (r >> 2) + 4 * hi;
    u16* hp = Op + (size_t)kvh * 4194304 + ((size_t)bh * 2048 + qt + qr) * 64;
    hp[lq] = f2bf(o0[r]);
    hp[32 + lq] = f2bf(o1[r]);
  }
  if (lq == 0) {  // lacc rows are the per-q sums (replicated across d-cols)
#pragma unroll
    for (int r = 0; r < 16; ++r) {
      int qr = (r & 3) + 8 * (r >> 2) + 4 * hi;
      Lp[(size_t)kvh * 65536 + (size_t)bh * 2048 + qt + qr] = lacc[r];
    }
  }
}

// ---------------- combine: Hd = (Op0 + Op1) / (L0 + L1) ----------------
__global__ __launch_bounds__(256) void combine_kernel(const u16* __restrict__ Op,
                                                      const float* __restrict__ Lp,
                                                      u16* __restrict__ Hd) {
  const int idx = blockIdx.x * 256 + threadIdx.x;  // 524288 threads: row g, d-oct j
  const int g = idx >> 3, j = idx & 7;
  const float fac = 1.f / (Lp[g] + Lp[65536 + g]);
  const u16* a = Op + (size_t)g * 64 + j * 8;
  const u16* bptr = a + 4194304;
  u32x4 va = *(const u32x4*)a;
  u32x4 vb = *(const u32x4*)bptr;
  const u16* pa = (const u16*)&va;
  const u16* pb = (const u16*)&vb;
  u32x4 outv;
  u16* po = (u16*)&outv;
#pragma unroll
  for (int e = 0; e < 8; ++e) po[e] = f2bf((bf2f(pa[e]) + bf2f(pb[e])) * fac);
  *(u32x4*)(Hd + (size_t)g * 64 + j * 8) = outv;
}

// ---------------- launch ----------------
extern "C" void kernel_launch(void* const* d_in, const int* in_sizes, int n_in,
                              void* d_out, int out_size, void* d_ws, size_t ws_size,
                              hipStream_t stream) {
  const float* Q = (const float*)d_in[0];
  const float* K = (const float*)d_in[1];
  const float* V = (const float*)d_in[2];
  const float* WQ = (const float*)d_in[3];
  const float* WK = (const float*)d_in[4];
  const float* WV = (const float*)d_in[5];
  const float* WO = (const float*)d_in[6];
  float* out = (float*)d_out;

  size_t off = 0;
  char* ws = (char*)d_ws;
  auto nxt = [&](size_t n) { void* p = ws + off; off += (n + 255) & ~(size_t)255; return p; };
  u16* Qb = (u16*)nxt(3ull * 4096 * 1024 * 2);   // Qb,Kb,Vb contiguous (dead after proj GEMM)
  u16* Qi = (u16*)nxt(3ull * 4096 * 1024 * 2);   // Qi,Ki,Vi contiguous
  u16* Vtb = (u16*)nxt(4096ull * 1024 * 2);
  u16* Hd = (u16*)nxt(4096ull * 1024 * 2);
  u16* Wt = (u16*)nxt(3ull * 1048576 * 2);
  u16* Wot = (u16*)nxt(1048576ull * 2);
  u16* Ki = Qi + 4194304;
  u16* Vi = Qi + 2 * 4194304;
  // attention partials alias the dead Qb region (16.8 MB + 0.5 MB < 24 MB)
  u16* Op = Qb;                                   // [2][32*2048][64] bf16
  float* Lp = (float*)(Qb + 2ull * 4194304);      // [2][65536] f32

  prep_kernel<<<4096, 256, 0, stream>>>(Q, K, V, WQ, WK, WV, WO, Qb, Qb + 4194304,
                                        Qb + 2 * 4194304, Wt, Wot);

  // fused Q/K/V projections: z picks (A, W, C) triple
  gemm_kernel<1><<<dim3(32, 8, 3), 256, 0, stream>>>(Qb, Wt, Qi);

  transposeV_kernel<<<dim3(32, 32), 256, 0, stream>>>(Vi, Vtb);

  attn_kernel<<<1024, 256, 0, stream>>>(Qi, Ki, Vtb, Op, Lp);

  combine_kernel<<<2048, 256, 0, stream>>>(Op, Lp, Hd);

  gemm_kernel<0><<<dim3(32, 8, 1), 256, 0, stream>>>(Hd, Wot, out);
}

// Round 12
// 152.891 us; speedup vs baseline: 1.0080x; 1.0080x over previous
//
#include <hip/hip_runtime.h>
#include <hip/hip_bf16.h>
#include <stdint.h>

typedef unsigned short u16;
typedef unsigned int u32;
typedef __attribute__((ext_vector_type(4))) float f32x4;
typedef __attribute__((ext_vector_type(16))) float f32x16;
typedef __attribute__((ext_vector_type(8))) short bf16x8;
typedef __attribute__((ext_vector_type(4))) unsigned int u32x4;
typedef __attribute__((ext_vector_type(2))) unsigned int u32x2;

#define DEV __device__ __forceinline__

DEV u16 f2bf(float f) {
  union { float f; uint32_t u; } v; v.f = f;
  uint32_t u = v.u;
  return (u16)((u + 0x7fffu + ((u >> 16) & 1u)) >> 16);
}
DEV float bf2f(u16 h) {
  union { uint32_t u; float f; } v; v.u = ((uint32_t)h) << 16;
  return v.f;
}

DEV u32 cvtpk(float a, float b) {  // D.lo = bf16(a), D.hi = bf16(b), RNE
  u32 r;
  asm("v_cvt_pk_bf16_f32 %0, %1, %2" : "=v"(r) : "v"(a), "v"(b));
  return r;
}

// v_permlane32_swap_b32 a, b: a' = [a.lo32lanes, b.lo32lanes], b' = [a.hi, b.hi]
DEV void plswap(u32& a, u32& b) {
  asm("v_permlane32_swap_b32 %0, %1" : "+v"(a), "+v"(b));
}

DEV void gload_lds16(const u16* g, u16* l) {
  __builtin_amdgcn_global_load_lds(
      (const __attribute__((address_space(1))) void*)g,
      (__attribute__((address_space(3))) void*)l, 16, 0, 0);
}

// ---------------- prep: fp32 -> bf16 + transposed weights ----------------
__global__ __launch_bounds__(256) void prep_kernel(
    const float* __restrict__ Q, const float* __restrict__ K, const float* __restrict__ V,
    const float* __restrict__ WQ, const float* __restrict__ WK, const float* __restrict__ WV,
    const float* __restrict__ WO,
    u16* __restrict__ Qb, u16* __restrict__ Kb, u16* __restrict__ Vb,
    u16* __restrict__ Wt, u16* __restrict__ Wot) {
  const int i = blockIdx.x * 256 + threadIdx.x;  // 1,048,576 threads
#pragma unroll
  for (int it = 0; it < 3; ++it) {
    int idx = it * 1048576 + i;
    int which = idx >> 20, j = idx & 1048575;
    const float* src = which == 0 ? Q : (which == 1 ? K : V);
    u16* dst = which == 0 ? Qb : (which == 1 ? Kb : Vb);
    float4 v = ((const float4*)src)[j];
    u32x2 pk;
    pk[0] = (u32)f2bf(v.x) | ((u32)f2bf(v.y) << 16);
    pk[1] = (u32)f2bf(v.z) | ((u32)f2bf(v.w) << 16);
    *(u32x2*)(dst + (size_t)j * 4) = pk;
  }
#pragma unroll
  for (int it = 0; it < 4; ++it) {
    int idx = it * 1048576 + i;
    if (idx < 3145728) {
      int p = idx >> 20, r = idx & 1048575;
      int n = r >> 10, d = r & 1023;
      int h = n >> 6, k = n & 63;
      const float* src = p == 0 ? WQ : (p == 1 ? WK : WV);
      Wt[idx] = f2bf(src[(h * 1024 + d) * 64 + k]);
    } else {
      int j = idx - 3145728;
      int c = j >> 10, k = j & 1023;
      Wot[j] = f2bf(WO[k * 1024 + c]);
    }
  }
}

// ---------------- GEMM: C[4096][1024] = A[4096][1024] * Bt^T, z-batched ----------------
// XCD swizzle: per z-slice (256 blocks), XCD x gets one contiguous N-panel (32 M-blocks)
// so its Bt panel (256 KB) stays resident in that XCD's private L2.
template <int OUT_BF16>
__global__ __launch_bounds__(256, 2) void gemm_kernel(const u16* __restrict__ A,
                                                      const u16* __restrict__ Bt,
                                                      void* __restrict__ Cout) {
  __shared__ __align__(16) u16 Alds[128 * 64];
  __shared__ __align__(16) u16 Blds[128 * 64];
  const size_t zo = blockIdx.z;
  A += zo * 4194304;
  Bt += zo * 1048576;
  const int tid = threadIdx.x;
  const int l = tid & 63, w = tid >> 6;
  const int wm = w >> 1, wn = w & 1;
  const int d = blockIdx.x + 32 * blockIdx.y;
  const int orig = (d & 7) * 32 + (d >> 3);
  const int tileM = (orig & 31) * 128, tileN = (orig >> 5) * 128;
  const int lr = l >> 3, lch = l & 7;

  f32x4 acc[4][4] = {};

  for (int kt = 0; kt < 16; ++kt) {
    const int k0 = kt * 64;
#pragma unroll
    for (int i = 0; i < 4; ++i) {
      int r = i * 32 + w * 8 + lr;
      int sch = lch ^ (r & 7);
      gload_lds16(A + (size_t)(tileM + r) * 1024 + k0 + sch * 8, Alds + i * 2048 + w * 512);
      gload_lds16(Bt + (size_t)(tileN + r) * 1024 + k0 + sch * 8, Blds + i * 2048 + w * 512);
    }
    __syncthreads();
    bf16x8 af[4][2], bfr[4][2];
#pragma unroll
    for (int m = 0; m < 4; ++m) {
#pragma unroll
      for (int kk = 0; kk < 2; ++kk) {
        int row = wm * 64 + m * 16 + (l & 15);
        int ch = ((l >> 4) + kk * 4) ^ (row & 7);
        af[m][kk] = *(const bf16x8*)(Alds + row * 64 + ch * 8);
        int rowb = wn * 64 + m * 16 + (l & 15);
        int chb = ((l >> 4) + kk * 4) ^ (rowb & 7);
        bfr[m][kk] = *(const bf16x8*)(Blds + rowb * 64 + chb * 8);
      }
    }
#pragma unroll
    for (int m = 0; m < 4; ++m)
#pragma unroll
      for (int n = 0; n < 4; ++n)
#pragma unroll
        for (int kk = 0; kk < 2; ++kk)
          acc[m][n] = __builtin_amdgcn_mfma_f32_16x16x32_bf16(af[m][kk], bfr[n][kk], acc[m][n], 0, 0, 0);
    __syncthreads();
  }
#pragma unroll
  for (int m = 0; m < 4; ++m) {
    int row0 = tileM + wm * 64 + m * 16 + ((l >> 4) << 2);
#pragma unroll
    for (int n = 0; n < 4; ++n) {
      int col = tileN + wn * 64 + n * 16 + (l & 15);
#pragma unroll
      for (int q = 0; q < 4; ++q) {
        if (OUT_BF16)
          ((u16*)Cout)[zo * 4194304 + (size_t)(row0 + q) * 1024 + col] = f2bf(acc[m][n][q]);
        else
          ((float*)Cout)[(size_t)(row0 + q) * 1024 + col] = acc[m][n][q];
      }
    }
  }
}

// ---------------- transpose Vi[4096][1024] -> Vt[(bh*64+dk)][2048] ----------------
__global__ __launch_bounds__(256) void transposeV_kernel(const u16* __restrict__ Vi,
                                                         u16* __restrict__ Vt) {
  __shared__ __align__(16) u16 tl[64][72];
  const int tid = threadIdx.x;
  const int st = blockIdx.x * 64;
  const int bh = blockIdx.y;
  const int b = bh >> 4, h = bh & 15;
#pragma unroll
  for (int i = 0; i < 2; ++i) {
    int idx = i * 256 + tid;
    int s = idx >> 3, ch = idx & 7;
    const u16* src = Vi + (size_t)(b * 2048 + st + s) * 1024 + h * 64 + ch * 8;
    u32x2 a = *(const u32x2*)src;
    u32x2 bb = *(const u32x2*)(src + 4);
    *(u32x2*)&tl[s][ch * 8] = a;
    *(u32x2*)&tl[s][ch * 8 + 4] = bb;
  }
  __syncthreads();
#pragma unroll
  for (int i = 0; i < 2; ++i) {
    int idx = i * 256 + tid;
    int dk = idx >> 3, ch = idx & 7;
    u32x4 outv;
    u16* tp = (u16*)&outv;
#pragma unroll
    for (int j = 0; j < 8; ++j) tp[j] = tl[ch * 8 + j][dk];
    *(u32x4*)(Vt + ((size_t)bh * 64 + dk) * 2048 + st + ch * 8) = outv;
  }
}

// ---------------- flash attention: LDS-staged K/V + in-register softmax ----------------
// r10-verified structure + r11-verified plswap. Row-sum back on VALU (r10 path: lacc's
// +16 AGPR cost occupancy more than its VALU saving was worth — r11 post-mortem).
// LB(256,4): ~92 regs/wave -> 4 waves/SIMD, 4 blocks/CU (LDS 4x32KB <= 160KB).
__global__ __launch_bounds__(256, 4) void attn_kernel(const u16* __restrict__ Qi,
                                                      const u16* __restrict__ Ki,
                                                      const u16* __restrict__ Vt,
                                                      u16* __restrict__ Op,
                                                      float* __restrict__ Lp) {
  __shared__ __align__(16) u16 Kl[2][4096];
  __shared__ __align__(16) u16 Vl[2][4096];
  const int tid = threadIdx.x;
  const int l = tid & 63, w = tid >> 6;
  const int lq = l & 31, hi = l >> 5;
  const int lr = l >> 3, lch = l & 7;
  // bijective XCD chunk swizzle: 1024 blocks, XCD dd%8 gets 128 contiguous (=4 bh)
  const int dd = blockIdx.x;
  const int orig = (dd & 7) * 128 + (dd >> 3);
  const int bh = orig >> 5;
  const int rem = orig & 31;
  const int qb = rem >> 1, kvh = rem & 1;
  const int b = bh >> 4, h = bh & 15;
  const int qt = qb * 128 + w * 32;
  const int tb = kvh * 1024;

  const u16* Kbase = Ki + (size_t)b * 2048 * 1024 + h * 64;
  const u16* Vbase = Vt + (size_t)bh * 64 * 2048;

  // Q B-frags (col q = lq, k = s*16 + hi*8 + j), prescaled by log2(e)/8 (exp2 domain)
  bf16x8 qf[4];
  {
    const u16* qp = Qi + (size_t)(b * 2048 + qt + lq) * 1024 + h * 64 + hi * 8;
#pragma unroll
    for (int s = 0; s < 4; ++s) {
      u32x4 t4 = *(const u32x4*)(qp + s * 16);
      u16* tp = (u16*)&t4;
#pragma unroll
      for (int j = 0; j < 8; ++j) tp[j] = f2bf(bf2f(tp[j]) * 0.1803368867f);
      qf[s] = *(bf16x8*)&t4;
    }
  }

  f32x16 o0 = {}, o1 = {};
  float l_r = 0.f;

  // stage tile `t` into buffer `bb`: K [64 t-rows][64 k], V^T [64 d-rows][64 t]
  auto STAGE = [&](int bb, int t) {
#pragma unroll
    for (int i = 0; i < 2; ++i) {
      int r = i * 32 + w * 8 + lr;
      int sch = lch ^ (r & 7);
      gload_lds16(Kbase + (size_t)(tb + t * 64 + r) * 1024 + sch * 8,
                  Kl[bb] + i * 2048 + w * 512);
      gload_lds16(Vbase + (size_t)r * 2048 + tb + t * 64 + sch * 8,
                  Vl[bb] + i * 2048 + w * 512);
    }
  };

  STAGE(0, 0);

#pragma unroll 2
  for (int tile = 0; tile < 16; ++tile) {
    const int cur = tile & 1;
    __syncthreads();  // compiler drains vmcnt: staged tile `cur` ready
    if (tile + 1 < 16) STAGE(cur ^ 1, tile + 1);
    const u16* kl = Kl[cur];
    const u16* vl = Vl[cur];

    // S^T = K Q^T: two 32-t halves
    f32x16 s0 = {}, s1 = {};
    __builtin_amdgcn_s_setprio(1);
#pragma unroll
    for (int s = 0; s < 4; ++s) {
      int row = lq, c = s * 2 + hi;
      bf16x8 kf = *(const bf16x8*)(kl + row * 64 + (c ^ (row & 7)) * 8);
      s0 = __builtin_amdgcn_mfma_f32_32x32x16_bf16(kf, qf[s], s0, 0, 0, 0);
    }
#pragma unroll
    for (int s = 0; s < 4; ++s) {
      int row = 32 + lq, c = s * 2 + hi;
      bf16x8 kf = *(const bf16x8*)(kl + row * 64 + (c ^ (row & 7)) * 8);
      s1 = __builtin_amdgcn_mfma_f32_32x32x16_bf16(kf, qf[s], s1, 0, 0, 0);
    }
    __builtin_amdgcn_s_setprio(0);

    // P = exp2(S); row-sum on VALU (tree); pack to bf16; half-swap via permlane32
    float rs = 0.f;
    bf16x8 pa[4];
#pragma unroll
    for (int s4 = 0; s4 < 4; ++s4) {
      const int rb = 8 * (s4 & 1);
      float p[8];
#pragma unroll
      for (int j = 0; j < 8; ++j) {
        float sv = (s4 < 2) ? ((const float*)&s0)[rb + j] : ((const float*)&s1)[rb + j];
        p[j] = exp2f(sv);
      }
      rs += ((p[0] + p[1]) + (p[2] + p[3])) + ((p[4] + p[5]) + (p[6] + p[7]));
      u32 w10 = cvtpk(p[0], p[1]);
      u32 w11 = cvtpk(p[2], p[3]);
      u32 w20 = cvtpk(p[4], p[5]);
      u32 w21 = cvtpk(p[6], p[7]);
      plswap(w10, w20);  // w10 -> [w10.lo, w20.lo]; w20 -> [w10.hi, w20.hi]
      plswap(w11, w21);
      u32x4 af;
      af[0] = w10;
      af[1] = w11;
      af[2] = w20;
      af[3] = w21;
      pa[s4] = *(bf16x8*)&af;  // t-window s4*16
    }
    rs += __shfl_xor(rs, 32, 64);
    l_r += rs;

    // O += P V
    __builtin_amdgcn_s_setprio(1);
#pragma unroll
    for (int s4 = 0; s4 < 4; ++s4) {
      int rowd = lq, c = s4 * 2 + hi;
      bf16x8 vf = *(const bf16x8*)(vl + rowd * 64 + (c ^ (rowd & 7)) * 8);
      o0 = __builtin_amdgcn_mfma_f32_32x32x16_bf16(pa[s4], vf, o0, 0, 0, 0);
    }
#pragma unroll
    for (int s4 = 0; s4 < 4; ++s4) {
      int rowd = 32 + lq, c = s4 * 2 + hi;
      bf16x8 vf = *(const bf16x8*)(vl + rowd * 64 + (c ^ (rowd & 7)) * 8);
      o1 = __builtin_amdgcn_mfma_f32_32x32x16_bf16(pa[s4], vf, o1, 0, 0, 0);
    }
    __builtin_amdgcn_s_setprio(0);
  }

  // write unnormalized partials (D-layout: q(reg r) = (r&3)+8*(r>>2)+4*hi, d-col = lq)
#pragma unroll
  for (int r = 0; r < 16; ++r) {
    int qr = (r & 3) + 8 * (r >> 2) + 4 * hi;
    u16* hp = Op + (size_t)kvh * 4194304 + ((size_t)bh * 2048 + qt + qr) * 64;
    hp[lq] = f2bf(o0[r]);
    hp[32 + lq] = f2bf(o1[r]);
  }
  if (hi == 0) Lp[(size_t)kvh * 65536 + (size_t)bh * 2048 + qt + lq] = l_r;
}

// ---------------- combine: Hd = (Op0 + Op1) / (L0 + L1) ----------------
__global__ __launch_bounds__(256) void combine_kernel(const u16* __restrict__ Op,
                                                      const float* __restrict__ Lp,
                                                      u16* __restrict__ Hd) {
  const int idx = blockIdx.x * 256 + threadIdx.x;  // 524288 threads: row g, d-oct j
  const int g = idx >> 3, j = idx & 7;
  const float fac = 1.f / (Lp[g] + Lp[65536 + g]);
  const u16* a = Op + (size_t)g * 64 + j * 8;
  const u16* bptr = a + 4194304;
  u32x4 va = *(const u32x4*)a;
  u32x4 vb = *(const u32x4*)bptr;
  const u16* pa = (const u16*)&va;
  const u16* pb = (const u16*)&vb;
  u32x4 outv;
  u16* po = (u16*)&outv;
#pragma unroll
  for (int e = 0; e < 8; ++e) po[e] = f2bf((bf2f(pa[e]) + bf2f(pb[e])) * fac);
  *(u32x4*)(Hd + (size_t)g * 64 + j * 8) = outv;
}

// ---------------- launch ----------------
extern "C" void kernel_launch(void* const* d_in, const int* in_sizes, int n_in,
                              void* d_out, int out_size, void* d_ws, size_t ws_size,
                              hipStream_t stream) {
  const float* Q = (const float*)d_in[0];
  const float* K = (const float*)d_in[1];
  const float* V = (const float*)d_in[2];
  const float* WQ = (const float*)d_in[3];
  const float* WK = (const float*)d_in[4];
  const float* WV = (const float*)d_in[5];
  const float* WO = (const float*)d_in[6];
  float* out = (float*)d_out;

  size_t off = 0;
  char* ws = (char*)d_ws;
  auto nxt = [&](size_t n) { void* p = ws + off; off += (n + 255) & ~(size_t)255; return p; };
  u16* Qb = (u16*)nxt(3ull * 4096 * 1024 * 2);   // Qb,Kb,Vb contiguous (dead after proj GEMM)
  u16* Qi = (u16*)nxt(3ull * 4096 * 1024 * 2);   // Qi,Ki,Vi contiguous
  u16* Vtb = (u16*)nxt(4096ull * 1024 * 2);
  u16* Hd = (u16*)nxt(4096ull * 1024 * 2);
  u16* Wt = (u16*)nxt(3ull * 1048576 * 2);
  u16* Wot = (u16*)nxt(1048576ull * 2);
  u16* Ki = Qi + 4194304;
  u16* Vi = Qi + 2 * 4194304;
  // attention partials alias the dead Qb region (16.8 MB + 0.5 MB < 24 MB)
  u16* Op = Qb;                                   // [2][32*2048][64] bf16
  float* Lp = (float*)(Qb + 2ull * 4194304);      // [2][65536] f32

  prep_kernel<<<4096, 256, 0, stream>>>(Q, K, V, WQ, WK, WV, WO, Qb, Qb + 4194304,
                                        Qb + 2 * 4194304, Wt, Wot);

  // fused Q/K/V projections: z picks (A, W, C) triple
  gemm_kernel<1><<<dim3(32, 8, 3), 256, 0, stream>>>(Qb, Wt, Qi);

  transposeV_kernel<<<dim3(32, 32), 256, 0, stream>>>(Vi, Vtb);

  attn_kernel<<<1024, 256, 0, stream>>>(Qi, Ki, Vtb, Op, Lp);

  combine_kernel<<<2048, 256, 0, stream>>>(Op, Lp, Hd);

  gemm_kernel<0><<<dim3(32, 8, 1), 256, 0, stream>>>(Hd, Wot, out);
}

// Round 13
// 139.972 us; speedup vs baseline: 1.1010x; 1.0923x over previous
//
#include <hip/hip_runtime.h>
#include <hip/hip_bf16.h>
#include <stdint.h>

typedef unsigned short u16;
typedef unsigned int u32;
typedef __attribute__((ext_vector_type(4))) float f32x4;
typedef __attribute__((ext_vector_type(16))) float f32x16;
typedef __attribute__((ext_vector_type(8))) short bf16x8;
typedef __attribute__((ext_vector_type(4))) unsigned int u32x4;
typedef __attribute__((ext_vector_type(2))) unsigned int u32x2;

#define DEV __device__ __forceinline__

DEV u16 f2bf(float f) {
  union { float f; uint32_t u; } v; v.f = f;
  uint32_t u = v.u;
  return (u16)((u + 0x7fffu + ((u >> 16) & 1u)) >> 16);
}
DEV float bf2f(u16 h) {
  union { uint32_t u; float f; } v; v.u = ((uint32_t)h) << 16;
  return v.f;
}

DEV u32 cvtpk(float a, float b) {  // D.lo = bf16(a), D.hi = bf16(b), RNE
  u32 r;
  asm("v_cvt_pk_bf16_f32 %0, %1, %2" : "=v"(r) : "v"(a), "v"(b));
  return r;
}

// v_permlane32_swap_b32 a, b: a' = [a.lo32lanes, b.lo32lanes], b' = [a.hi, b.hi]
DEV void plswap(u32& a, u32& b) {
  asm("v_permlane32_swap_b32 %0, %1" : "+v"(a), "+v"(b));
}

// raw 2^x — single quarter-rate trans op (libm exp2f carries range/denorm guards)
DEV float fexp2(float x) {
  float r;
  asm("v_exp_f32 %0, %1" : "=v"(r) : "v"(x));
  return r;
}

DEV void gload_lds16(const u16* g, u16* l) {
  __builtin_amdgcn_global_load_lds(
      (const __attribute__((address_space(1))) void*)g,
      (__attribute__((address_space(3))) void*)l, 16, 0, 0);
}

// ---------------- prep: fp32 -> bf16 + transposed weights ----------------
__global__ __launch_bounds__(256) void prep_kernel(
    const float* __restrict__ Q, const float* __restrict__ K, const float* __restrict__ V,
    const float* __restrict__ WQ, const float* __restrict__ WK, const float* __restrict__ WV,
    const float* __restrict__ WO,
    u16* __restrict__ Qb, u16* __restrict__ Kb, u16* __restrict__ Vb,
    u16* __restrict__ Wt, u16* __restrict__ Wot) {
  const int i = blockIdx.x * 256 + threadIdx.x;  // 1,048,576 threads
#pragma unroll
  for (int it = 0; it < 3; ++it) {
    int idx = it * 1048576 + i;
    int which = idx >> 20, j = idx & 1048575;
    const float* src = which == 0 ? Q : (which == 1 ? K : V);
    u16* dst = which == 0 ? Qb : (which == 1 ? Kb : Vb);
    float4 v = ((const float4*)src)[j];
    u32x2 pk;
    pk[0] = (u32)f2bf(v.x) | ((u32)f2bf(v.y) << 16);
    pk[1] = (u32)f2bf(v.z) | ((u32)f2bf(v.w) << 16);
    *(u32x2*)(dst + (size_t)j * 4) = pk;
  }
#pragma unroll
  for (int it = 0; it < 4; ++it) {
    int idx = it * 1048576 + i;
    if (idx < 3145728) {
      int p = idx >> 20, r = idx & 1048575;
      int n = r >> 10, d = r & 1023;
      int h = n >> 6, k = n & 63;
      const float* src = p == 0 ? WQ : (p == 1 ? WK : WV);
      Wt[idx] = f2bf(src[(h * 1024 + d) * 64 + k]);
    } else {
      int j = idx - 3145728;
      int c = j >> 10, k = j & 1023;
      Wot[j] = f2bf(WO[k * 1024 + c]);
    }
  }
}

// ---------------- GEMM: C[4096][1024] = A[4096][1024] * Bt^T, z-batched ----------------
// XCD swizzle: per z-slice (256 blocks), XCD x gets one contiguous N-panel (32 M-blocks)
// so its Bt panel (256 KB) stays resident in that XCD's private L2.
template <int OUT_BF16>
__global__ __launch_bounds__(256, 2) void gemm_kernel(const u16* __restrict__ A,
                                                      const u16* __restrict__ Bt,
                                                      void* __restrict__ Cout) {
  __shared__ __align__(16) u16 Alds[128 * 64];
  __shared__ __align__(16) u16 Blds[128 * 64];
  const size_t zo = blockIdx.z;
  A += zo * 4194304;
  Bt += zo * 1048576;
  const int tid = threadIdx.x;
  const int l = tid & 63, w = tid >> 6;
  const int wm = w >> 1, wn = w & 1;
  const int d = blockIdx.x + 32 * blockIdx.y;
  const int orig = (d & 7) * 32 + (d >> 3);
  const int tileM = (orig & 31) * 128, tileN = (orig >> 5) * 128;
  const int lr = l >> 3, lch = l & 7;

  f32x4 acc[4][4] = {};

  for (int kt = 0; kt < 16; ++kt) {
    const int k0 = kt * 64;
#pragma unroll
    for (int i = 0; i < 4; ++i) {
      int r = i * 32 + w * 8 + lr;
      int sch = lch ^ (r & 7);
      gload_lds16(A + (size_t)(tileM + r) * 1024 + k0 + sch * 8, Alds + i * 2048 + w * 512);
      gload_lds16(Bt + (size_t)(tileN + r) * 1024 + k0 + sch * 8, Blds + i * 2048 + w * 512);
    }
    __syncthreads();
    bf16x8 af[4][2], bfr[4][2];
#pragma unroll
    for (int m = 0; m < 4; ++m) {
#pragma unroll
      for (int kk = 0; kk < 2; ++kk) {
        int row = wm * 64 + m * 16 + (l & 15);
        int ch = ((l >> 4) + kk * 4) ^ (row & 7);
        af[m][kk] = *(const bf16x8*)(Alds + row * 64 + ch * 8);
        int rowb = wn * 64 + m * 16 + (l & 15);
        int chb = ((l >> 4) + kk * 4) ^ (rowb & 7);
        bfr[m][kk] = *(const bf16x8*)(Blds + rowb * 64 + chb * 8);
      }
    }
#pragma unroll
    for (int m = 0; m < 4; ++m)
#pragma unroll
      for (int n = 0; n < 4; ++n)
#pragma unroll
        for (int kk = 0; kk < 2; ++kk)
          acc[m][n] = __builtin_amdgcn_mfma_f32_16x16x32_bf16(af[m][kk], bfr[n][kk], acc[m][n], 0, 0, 0);
    __syncthreads();
  }
#pragma unroll
  for (int m = 0; m < 4; ++m) {
    int row0 = tileM + wm * 64 + m * 16 + ((l >> 4) << 2);
#pragma unroll
    for (int n = 0; n < 4; ++n) {
      int col = tileN + wn * 64 + n * 16 + (l & 15);
#pragma unroll
      for (int q = 0; q < 4; ++q) {
        if (OUT_BF16)
          ((u16*)Cout)[zo * 4194304 + (size_t)(row0 + q) * 1024 + col] = f2bf(acc[m][n][q]);
        else
          ((float*)Cout)[(size_t)(row0 + q) * 1024 + col] = acc[m][n][q];
      }
    }
  }
}

// ---------------- transpose Vi[4096][1024] -> Vt[(bh*64+dk)][2048] ----------------
__global__ __launch_bounds__(256) void transposeV_kernel(const u16* __restrict__ Vi,
                                                         u16* __restrict__ Vt) {
  __shared__ __align__(16) u16 tl[64][72];
  const int tid = threadIdx.x;
  const int st = blockIdx.x * 64;
  const int bh = blockIdx.y;
  const int b = bh >> 4, h = bh & 15;
#pragma unroll
  for (int i = 0; i < 2; ++i) {
    int idx = i * 256 + tid;
    int s = idx >> 3, ch = idx & 7;
    const u16* src = Vi + (size_t)(b * 2048 + st + s) * 1024 + h * 64 + ch * 8;
    u32x2 a = *(const u32x2*)src;
    u32x2 bb = *(const u32x2*)(src + 4);
    *(u32x2*)&tl[s][ch * 8] = a;
    *(u32x2*)&tl[s][ch * 8 + 4] = bb;
  }
  __syncthreads();
#pragma unroll
  for (int i = 0; i < 2; ++i) {
    int idx = i * 256 + tid;
    int dk = idx >> 3, ch = idx & 7;
    u32x4 outv;
    u16* tp = (u16*)&outv;
#pragma unroll
    for (int j = 0; j < 8; ++j) tp[j] = tl[ch * 8 + j][dk];
    *(u32x4*)(Vt + ((size_t)bh * 64 + dk) * 2048 + st + ch * 8) = outv;
  }
}

// ---------------- flash attention: LDS-staged K/V + in-register softmax ----------------
// r12-verified structure (plswap + VALU row-sum + LB(256,4)). This round: exp2f -> raw
// v_exp_f32 asm (libm exp2f is multi-instruction; r12 VALU:MFMA ratio exposed it).
__global__ __launch_bounds__(256, 4) void attn_kernel(const u16* __restrict__ Qi,
                                                      const u16* __restrict__ Ki,
                                                      const u16* __restrict__ Vt,
                                                      u16* __restrict__ Op,
                                                      float* __restrict__ Lp) {
  __shared__ __align__(16) u16 Kl[2][4096];
  __shared__ __align__(16) u16 Vl[2][4096];
  const int tid = threadIdx.x;
  const int l = tid & 63, w = tid >> 6;
  const int lq = l & 31, hi = l >> 5;
  const int lr = l >> 3, lch = l & 7;
  // bijective XCD chunk swizzle: 1024 blocks, XCD dd%8 gets 128 contiguous (=4 bh)
  const int dd = blockIdx.x;
  const int orig = (dd & 7) * 128 + (dd >> 3);
  const int bh = orig >> 5;
  const int rem = orig & 31;
  const int qb = rem >> 1, kvh = rem & 1;
  const int b = bh >> 4, h = bh & 15;
  const int qt = qb * 128 + w * 32;
  const int tb = kvh * 1024;

  const u16* Kbase = Ki + (size_t)b * 2048 * 1024 + h * 64;
  const u16* Vbase = Vt + (size_t)bh * 64 * 2048;

  // Q B-frags (col q = lq, k = s*16 + hi*8 + j), prescaled by log2(e)/8 (exp2 domain)
  bf16x8 qf[4];
  {
    const u16* qp = Qi + (size_t)(b * 2048 + qt + lq) * 1024 + h * 64 + hi * 8;
#pragma unroll
    for (int s = 0; s < 4; ++s) {
      u32x4 t4 = *(const u32x4*)(qp + s * 16);
      u16* tp = (u16*)&t4;
#pragma unroll
      for (int j = 0; j < 8; ++j) tp[j] = f2bf(bf2f(tp[j]) * 0.1803368867f);
      qf[s] = *(bf16x8*)&t4;
    }
  }

  f32x16 o0 = {}, o1 = {};
  float l_r = 0.f;

  // stage tile `t` into buffer `bb`: K [64 t-rows][64 k], V^T [64 d-rows][64 t]
  auto STAGE = [&](int bb, int t) {
#pragma unroll
    for (int i = 0; i < 2; ++i) {
      int r = i * 32 + w * 8 + lr;
      int sch = lch ^ (r & 7);
      gload_lds16(Kbase + (size_t)(tb + t * 64 + r) * 1024 + sch * 8,
                  Kl[bb] + i * 2048 + w * 512);
      gload_lds16(Vbase + (size_t)r * 2048 + tb + t * 64 + sch * 8,
                  Vl[bb] + i * 2048 + w * 512);
    }
  };

  STAGE(0, 0);

#pragma unroll 2
  for (int tile = 0; tile < 16; ++tile) {
    const int cur = tile & 1;
    __syncthreads();  // compiler drains vmcnt: staged tile `cur` ready
    if (tile + 1 < 16) STAGE(cur ^ 1, tile + 1);
    const u16* kl = Kl[cur];
    const u16* vl = Vl[cur];

    // S^T = K Q^T: two 32-t halves
    f32x16 s0 = {}, s1 = {};
    __builtin_amdgcn_s_setprio(1);
#pragma unroll
    for (int s = 0; s < 4; ++s) {
      int row = lq, c = s * 2 + hi;
      bf16x8 kf = *(const bf16x8*)(kl + row * 64 + (c ^ (row & 7)) * 8);
      s0 = __builtin_amdgcn_mfma_f32_32x32x16_bf16(kf, qf[s], s0, 0, 0, 0);
    }
#pragma unroll
    for (int s = 0; s < 4; ++s) {
      int row = 32 + lq, c = s * 2 + hi;
      bf16x8 kf = *(const bf16x8*)(kl + row * 64 + (c ^ (row & 7)) * 8);
      s1 = __builtin_amdgcn_mfma_f32_32x32x16_bf16(kf, qf[s], s1, 0, 0, 0);
    }
    __builtin_amdgcn_s_setprio(0);

    // P = exp2(S) via raw v_exp_f32; row-sum tree on VALU; pack; permlane half-swap
    float rs = 0.f;
    bf16x8 pa[4];
#pragma unroll
    for (int s4 = 0; s4 < 4; ++s4) {
      const int rb = 8 * (s4 & 1);
      float p[8];
#pragma unroll
      for (int j = 0; j < 8; ++j) {
        float sv = (s4 < 2) ? ((const float*)&s0)[rb + j] : ((const float*)&s1)[rb + j];
        p[j] = fexp2(sv);
      }
      rs += ((p[0] + p[1]) + (p[2] + p[3])) + ((p[4] + p[5]) + (p[6] + p[7]));
      u32 w10 = cvtpk(p[0], p[1]);
      u32 w11 = cvtpk(p[2], p[3]);
      u32 w20 = cvtpk(p[4], p[5]);
      u32 w21 = cvtpk(p[6], p[7]);
      plswap(w10, w20);  // w10 -> [w10.lo, w20.lo]; w20 -> [w10.hi, w20.hi]
      plswap(w11, w21);
      u32x4 af;
      af[0] = w10;
      af[1] = w11;
      af[2] = w20;
      af[3] = w21;
      pa[s4] = *(bf16x8*)&af;  // t-window s4*16
    }
    rs += __shfl_xor(rs, 32, 64);
    l_r += rs;

    // O += P V
    __builtin_amdgcn_s_setprio(1);
#pragma unroll
    for (int s4 = 0; s4 < 4; ++s4) {
      int rowd = lq, c = s4 * 2 + hi;
      bf16x8 vf = *(const bf16x8*)(vl + rowd * 64 + (c ^ (rowd & 7)) * 8);
      o0 = __builtin_amdgcn_mfma_f32_32x32x16_bf16(pa[s4], vf, o0, 0, 0, 0);
    }
#pragma unroll
    for (int s4 = 0; s4 < 4; ++s4) {
      int rowd = 32 + lq, c = s4 * 2 + hi;
      bf16x8 vf = *(const bf16x8*)(vl + rowd * 64 + (c ^ (rowd & 7)) * 8);
      o1 = __builtin_amdgcn_mfma_f32_32x32x16_bf16(pa[s4], vf, o1, 0, 0, 0);
    }
    __builtin_amdgcn_s_setprio(0);
  }

  // write unnormalized partials (D-layout: q(reg r) = (r&3)+8*(r>>2)+4*hi, d-col = lq)
#pragma unroll
  for (int r = 0; r < 16; ++r) {
    int qr = (r & 3) + 8 * (r >> 2) + 4 * hi;
    u16* hp = Op + (size_t)kvh * 4194304 + ((size_t)bh * 2048 + qt + qr) * 64;
    hp[lq] = f2bf(o0[r]);
    hp[32 + lq] = f2bf(o1[r]);
  }
  if (hi == 0) Lp[(size_t)kvh * 65536 + (size_t)bh * 2048 + qt + lq] = l_r;
}

// ---------------- combine: Hd = (Op0 + Op1) / (L0 + L1) ----------------
__global__ __launch_bounds__(256) void combine_kernel(const u16* __restrict__ Op,
                                                      const float* __restrict__ Lp,
                                                      u16* __restrict__ Hd) {
  const int idx = blockIdx.x * 256 + threadIdx.x;  // 524288 threads: row g, d-oct j
  const int g = idx >> 3, j = idx & 7;
  const float fac = 1.f / (Lp[g] + Lp[65536 + g]);
  const u16* a = Op + (size_t)g * 64 + j * 8;
  const u16* bptr = a + 4194304;
  u32x4 va = *(const u32x4*)a;
  u32x4 vb = *(const u32x4*)bptr;
  const u16* pa = (const u16*)&va;
  const u16* pb = (const u16*)&vb;
  u32x4 outv;
  u16* po = (u16*)&outv;
#pragma unroll
  for (int e = 0; e < 8; ++e) po[e] = f2bf((bf2f(pa[e]) + bf2f(pb[e])) * fac);
  *(u32x4*)(Hd + (size_t)g * 64 + j * 8) = outv;
}

// ---------------- launch ----------------
extern "C" void kernel_launch(void* const* d_in, const int* in_sizes, int n_in,
                              void* d_out, int out_size, void* d_ws, size_t ws_size,
                              hipStream_t stream) {
  const float* Q = (const float*)d_in[0];
  const float* K = (const float*)d_in[1];
  const float* V = (const float*)d_in[2];
  const float* WQ = (const float*)d_in[3];
  const float* WK = (const float*)d_in[4];
  const float* WV = (const float*)d_in[5];
  const float* WO = (const float*)d_in[6];
  float* out = (float*)d_out;

  size_t off = 0;
  char* ws = (char*)d_ws;
  auto nxt = [&](size_t n) { void* p = ws + off; off += (n + 255) & ~(size_t)255; return p; };
  u16* Qb = (u16*)nxt(3ull * 4096 * 1024 * 2);   // Qb,Kb,Vb contiguous (dead after proj GEMM)
  u16* Qi = (u16*)nxt(3ull * 4096 * 1024 * 2);   // Qi,Ki,Vi contiguous
  u16* Vtb = (u16*)nxt(4096ull * 1024 * 2);
  u16* Hd = (u16*)nxt(4096ull * 1024 * 2);
  u16* Wt = (u16*)nxt(3ull * 1048576 * 2);
  u16* Wot = (u16*)nxt(1048576ull * 2);
  u16* Ki = Qi + 4194304;
  u16* Vi = Qi + 2 * 4194304;
  // attention partials alias the dead Qb region (16.8 MB + 0.5 MB < 24 MB)
  u16* Op = Qb;                                   // [2][32*2048][64] bf16
  float* Lp = (float*)(Qb + 2ull * 4194304);      // [2][65536] f32

  prep_kernel<<<4096, 256, 0, stream>>>(Q, K, V, WQ, WK, WV, WO, Qb, Qb + 4194304,
                                        Qb + 2 * 4194304, Wt, Wot);

  // fused Q/K/V projections: z picks (A, W, C) triple
  gemm_kernel<1><<<dim3(32, 8, 3), 256, 0, stream>>>(Qb, Wt, Qi);

  transposeV_kernel<<<dim3(32, 32), 256, 0, stream>>>(Vi, Vtb);

  attn_kernel<<<1024, 256, 0, stream>>>(Qi, Ki, Vtb, Op, Lp);

  combine_kernel<<<2048, 256, 0, stream>>>(Op, Lp, Hd);

  gemm_kernel<0><<<dim3(32, 8, 1), 256, 0, stream>>>(Hd, Wot, out);
}

// Round 14
// 137.073 us; speedup vs baseline: 1.1243x; 1.0211x over previous
//
#include <hip/hip_runtime.h>
#include <hip/hip_bf16.h>
#include <stdint.h>

typedef unsigned short u16;
typedef unsigned int u32;
typedef __attribute__((ext_vector_type(4))) float f32x4;
typedef __attribute__((ext_vector_type(16))) float f32x16;
typedef __attribute__((ext_vector_type(8))) short bf16x8;
typedef __attribute__((ext_vector_type(4))) unsigned int u32x4;
typedef __attribute__((ext_vector_type(2))) unsigned int u32x2;

#define DEV __device__ __forceinline__

DEV u16 f2bf(float f) {
  union { float f; uint32_t u; } v; v.f = f;
  uint32_t u = v.u;
  return (u16)((u + 0x7fffu + ((u >> 16) & 1u)) >> 16);
}
DEV float bf2f(u16 h) {
  union { uint32_t u; float f; } v; v.u = ((uint32_t)h) << 16;
  return v.f;
}

DEV u32 cvtpk(float a, float b) {  // D.lo = bf16(a), D.hi = bf16(b), RNE
  u32 r;
  asm("v_cvt_pk_bf16_f32 %0, %1, %2" : "=v"(r) : "v"(a), "v"(b));
  return r;
}

// v_permlane32_swap_b32 a, b: a' = [a.lo32lanes, b.lo32lanes], b' = [a.hi, b.hi]
DEV void plswap(u32& a, u32& b) {
  asm("v_permlane32_swap_b32 %0, %1" : "+v"(a), "+v"(b));
}

// raw 2^x — single quarter-rate trans op (libm exp2f carries range/denorm guards)
DEV float fexp2(float x) {
  float r;
  asm("v_exp_f32 %0, %1" : "=v"(r) : "v"(x));
  return r;
}

DEV void gload_lds16(const u16* g, u16* l) {
  __builtin_amdgcn_global_load_lds(
      (const __attribute__((address_space(1))) void*)g,
      (__attribute__((address_space(3))) void*)l, 16, 0, 0);
}

// ---------------- prep: fp32 -> bf16 for Q/K/V (coalesced float4) ----------------
__global__ __launch_bounds__(256) void prep_kernel(
    const float* __restrict__ Q, const float* __restrict__ K, const float* __restrict__ V,
    u16* __restrict__ Qb, u16* __restrict__ Kb, u16* __restrict__ Vb) {
  const int i = blockIdx.x * 256 + threadIdx.x;  // 1,048,576 threads
#pragma unroll
  for (int it = 0; it < 3; ++it) {
    int idx = it * 1048576 + i;
    int which = idx >> 20, j = idx & 1048575;
    const float* src = which == 0 ? Q : (which == 1 ? K : V);
    u16* dst = which == 0 ? Qb : (which == 1 ? Kb : Vb);
    float4 v = ((const float4*)src)[j];
    u32x2 pk;
    pk[0] = (u32)f2bf(v.x) | ((u32)f2bf(v.y) << 16);
    pk[1] = (u32)f2bf(v.z) | ((u32)f2bf(v.w) << 16);
    *(u32x2*)(dst + (size_t)j * 4) = pk;
  }
}

// ---------------- tiled weight transpose (coalesced both sides) ----------------
// blocks 0..767:  Wt[p][(h*64+k)][d] = W_p[h][d][k]   (64x64 tile (p,h,dt))
// blocks 768..1023: Wot[c][k] = WO[k][c]              (64x64 tile (kt,ct))
__global__ __launch_bounds__(256) void transposeW_kernel(
    const float* __restrict__ WQ, const float* __restrict__ WK, const float* __restrict__ WV,
    const float* __restrict__ WO, u16* __restrict__ Wt, u16* __restrict__ Wot) {
  __shared__ __align__(16) u16 tl[64][72];
  const int tid = threadIdx.x;
  const int bid = blockIdx.x;
  const float* src;
  u16* dst;
  int rstride;
  if (bid < 768) {
    int p = bid >> 8, rest = bid & 255;
    int h = rest >> 4, dt = rest & 15;
    const float* W = p == 0 ? WQ : (p == 1 ? WK : WV);
    src = W + (size_t)(h * 1024 + dt * 64) * 64;       // rows = d (stride 64 floats)
    dst = Wt + (size_t)p * 1048576 + (size_t)h * 64 * 1024 + dt * 64;  // rows = k
    rstride = 64;
  } else {
    int idx2 = bid - 768;
    int kt = idx2 >> 4, ct = idx2 & 15;
    src = WO + (size_t)kt * 64 * 1024 + ct * 64;       // rows = k (stride 1024 floats)
    dst = Wot + (size_t)ct * 64 * 1024 + kt * 64;      // rows = c
    rstride = 1024;
  }
  // load 64x64 f32 tile -> bf16 LDS (reads coalesced along source rows)
#pragma unroll
  for (int i = 0; i < 2; ++i) {
    int idx = i * 256 + tid;
    int row = idx >> 3, c8 = idx & 7;
    const float* sp = src + (size_t)row * rstride + c8 * 8;
    float4 a = *(const float4*)sp;
    float4 b = *(const float4*)(sp + 4);
    u32x4 pk;
    pk[0] = (u32)f2bf(a.x) | ((u32)f2bf(a.y) << 16);
    pk[1] = (u32)f2bf(a.z) | ((u32)f2bf(a.w) << 16);
    pk[2] = (u32)f2bf(b.x) | ((u32)f2bf(b.y) << 16);
    pk[3] = (u32)f2bf(b.z) | ((u32)f2bf(b.w) << 16);
    *(u32x4*)&tl[row][c8 * 8] = pk;
  }
  __syncthreads();
  // write transposed (16B vector stores, coalesced)
#pragma unroll
  for (int i = 0; i < 2; ++i) {
    int idx = i * 256 + tid;
    int row2 = idx >> 3, s8 = idx & 7;
    u32x4 outv;
    u16* tp = (u16*)&outv;
#pragma unroll
    for (int j = 0; j < 8; ++j) tp[j] = tl[s8 * 8 + j][row2];
    *(u32x4*)(dst + (size_t)row2 * 1024 + s8 * 8) = outv;
  }
}

// ---------------- GEMM: C[4096][1024] = A[4096][1024] * Bt^T, z-batched ----------------
template <int OUT_BF16>
__global__ __launch_bounds__(256, 2) void gemm_kernel(const u16* __restrict__ A,
                                                      const u16* __restrict__ Bt,
                                                      void* __restrict__ Cout) {
  __shared__ __align__(16) u16 Alds[128 * 64];
  __shared__ __align__(16) u16 Blds[128 * 64];
  const size_t zo = blockIdx.z;
  A += zo * 4194304;
  Bt += zo * 1048576;
  const int tid = threadIdx.x;
  const int l = tid & 63, w = tid >> 6;
  const int wm = w >> 1, wn = w & 1;
  const int d = blockIdx.x + 32 * blockIdx.y;
  const int orig = (d & 7) * 32 + (d >> 3);
  const int tileM = (orig & 31) * 128, tileN = (orig >> 5) * 128;
  const int lr = l >> 3, lch = l & 7;

  f32x4 acc[4][4] = {};

  for (int kt = 0; kt < 16; ++kt) {
    const int k0 = kt * 64;
#pragma unroll
    for (int i = 0; i < 4; ++i) {
      int r = i * 32 + w * 8 + lr;
      int sch = lch ^ (r & 7);
      gload_lds16(A + (size_t)(tileM + r) * 1024 + k0 + sch * 8, Alds + i * 2048 + w * 512);
      gload_lds16(Bt + (size_t)(tileN + r) * 1024 + k0 + sch * 8, Blds + i * 2048 + w * 512);
    }
    __syncthreads();
    bf16x8 af[4][2], bfr[4][2];
#pragma unroll
    for (int m = 0; m < 4; ++m) {
#pragma unroll
      for (int kk = 0; kk < 2; ++kk) {
        int row = wm * 64 + m * 16 + (l & 15);
        int ch = ((l >> 4) + kk * 4) ^ (row & 7);
        af[m][kk] = *(const bf16x8*)(Alds + row * 64 + ch * 8);
        int rowb = wn * 64 + m * 16 + (l & 15);
        int chb = ((l >> 4) + kk * 4) ^ (rowb & 7);
        bfr[m][kk] = *(const bf16x8*)(Blds + rowb * 64 + chb * 8);
      }
    }
#pragma unroll
    for (int m = 0; m < 4; ++m)
#pragma unroll
      for (int n = 0; n < 4; ++n)
#pragma unroll
        for (int kk = 0; kk < 2; ++kk)
          acc[m][n] = __builtin_amdgcn_mfma_f32_16x16x32_bf16(af[m][kk], bfr[n][kk], acc[m][n], 0, 0, 0);
    __syncthreads();
  }
#pragma unroll
  for (int m = 0; m < 4; ++m) {
    int row0 = tileM + wm * 64 + m * 16 + ((l >> 4) << 2);
#pragma unroll
    for (int n = 0; n < 4; ++n) {
      int col = tileN + wn * 64 + n * 16 + (l & 15);
#pragma unroll
      for (int q = 0; q < 4; ++q) {
        if (OUT_BF16)
          ((u16*)Cout)[zo * 4194304 + (size_t)(row0 + q) * 1024 + col] = f2bf(acc[m][n][q]);
        else
          ((float*)Cout)[(size_t)(row0 + q) * 1024 + col] = acc[m][n][q];
      }
    }
  }
}

// ---------------- transpose Vi[4096][1024] -> Vt[(bh*64+dk)][2048] ----------------
__global__ __launch_bounds__(256) void transposeV_kernel(const u16* __restrict__ Vi,
                                                         u16* __restrict__ Vt) {
  __shared__ __align__(16) u16 tl[64][72];
  const int tid = threadIdx.x;
  const int st = blockIdx.x * 64;
  const int bh = blockIdx.y;
  const int b = bh >> 4, h = bh & 15;
#pragma unroll
  for (int i = 0; i < 2; ++i) {
    int idx = i * 256 + tid;
    int s = idx >> 3, ch = idx & 7;
    const u16* src = Vi + (size_t)(b * 2048 + st + s) * 1024 + h * 64 + ch * 8;
    u32x2 a = *(const u32x2*)src;
    u32x2 bb = *(const u32x2*)(src + 4);
    *(u32x2*)&tl[s][ch * 8] = a;
    *(u32x2*)&tl[s][ch * 8 + 4] = bb;
  }
  __syncthreads();
#pragma unroll
  for (int i = 0; i < 2; ++i) {
    int idx = i * 256 + tid;
    int dk = idx >> 3, ch = idx & 7;
    u32x4 outv;
    u16* tp = (u16*)&outv;
#pragma unroll
    for (int j = 0; j < 8; ++j) tp[j] = tl[ch * 8 + j][dk];
    *(u32x4*)(Vt + ((size_t)bh * 64 + dk) * 2048 + st + ch * 8) = outv;
  }
}

// ---------------- flash attention: LDS-staged K/V + in-register softmax ----------------
// r13-verified structure; this round kv-split 4 (grid 2048) for occupancy: LDS 32KB ->
// 5 blocks/CU co-resident, ~20 waves/CU to hide barrier drains. Op[0..2] alias Qb,
// Op[3] aliases Hd (combined in-place 1:1).
__global__ __launch_bounds__(256, 4) void attn_kernel(const u16* __restrict__ Qi,
                                                      const u16* __restrict__ Ki,
                                                      const u16* __restrict__ Vt,
                                                      u16* __restrict__ Op,
                                                      u16* __restrict__ Op3,
                                                      float* __restrict__ Lp) {
  __shared__ __align__(16) u16 Kl[2][4096];
  __shared__ __align__(16) u16 Vl[2][4096];
  const int tid = threadIdx.x;
  const int l = tid & 63, w = tid >> 6;
  const int lq = l & 31, hi = l >> 5;
  const int lr = l >> 3, lch = l & 7;
  // bijective XCD chunk swizzle: 2048 blocks, XCD dd%8 gets 256 contiguous (=4 bh)
  const int dd = blockIdx.x;
  const int orig = (dd & 7) * 256 + (dd >> 3);
  const int bh = orig >> 6;
  const int rem = orig & 63;
  const int qb = rem >> 2, kvh = rem & 3;
  const int b = bh >> 4, h = bh & 15;
  const int qt = qb * 128 + w * 32;
  const int tb = kvh * 512;

  const u16* Kbase = Ki + (size_t)b * 2048 * 1024 + h * 64;
  const u16* Vbase = Vt + (size_t)bh * 64 * 2048;

  // Q B-frags (col q = lq, k = s*16 + hi*8 + j), prescaled by log2(e)/8 (exp2 domain)
  bf16x8 qf[4];
  {
    const u16* qp = Qi + (size_t)(b * 2048 + qt + lq) * 1024 + h * 64 + hi * 8;
#pragma unroll
    for (int s = 0; s < 4; ++s) {
      u32x4 t4 = *(const u32x4*)(qp + s * 16);
      u16* tp = (u16*)&t4;
#pragma unroll
      for (int j = 0; j < 8; ++j) tp[j] = f2bf(bf2f(tp[j]) * 0.1803368867f);
      qf[s] = *(bf16x8*)&t4;
    }
  }

  f32x16 o0 = {}, o1 = {};
  float l_r = 0.f;

  // stage tile `t` into buffer `bb`: K [64 t-rows][64 k], V^T [64 d-rows][64 t]
  auto STAGE = [&](int bb, int t) {
#pragma unroll
    for (int i = 0; i < 2; ++i) {
      int r = i * 32 + w * 8 + lr;
      int sch = lch ^ (r & 7);
      gload_lds16(Kbase + (size_t)(tb + t * 64 + r) * 1024 + sch * 8,
                  Kl[bb] + i * 2048 + w * 512);
      gload_lds16(Vbase + (size_t)r * 2048 + tb + t * 64 + sch * 8,
                  Vl[bb] + i * 2048 + w * 512);
    }
  };

  STAGE(0, 0);

#pragma unroll 2
  for (int tile = 0; tile < 8; ++tile) {
    const int cur = tile & 1;
    __syncthreads();  // compiler drains vmcnt: staged tile `cur` ready
    if (tile + 1 < 8) STAGE(cur ^ 1, tile + 1);
    const u16* kl = Kl[cur];
    const u16* vl = Vl[cur];

    // S^T = K Q^T: two 32-t halves
    f32x16 s0 = {}, s1 = {};
    __builtin_amdgcn_s_setprio(1);
#pragma unroll
    for (int s = 0; s < 4; ++s) {
      int row = lq, c = s * 2 + hi;
      bf16x8 kf = *(const bf16x8*)(kl + row * 64 + (c ^ (row & 7)) * 8);
      s0 = __builtin_amdgcn_mfma_f32_32x32x16_bf16(kf, qf[s], s0, 0, 0, 0);
    }
#pragma unroll
    for (int s = 0; s < 4; ++s) {
      int row = 32 + lq, c = s * 2 + hi;
      bf16x8 kf = *(const bf16x8*)(kl + row * 64 + (c ^ (row & 7)) * 8);
      s1 = __builtin_amdgcn_mfma_f32_32x32x16_bf16(kf, qf[s], s1, 0, 0, 0);
    }
    __builtin_amdgcn_s_setprio(0);

    // P = exp2(S) via raw v_exp_f32; row-sum tree on VALU; pack; permlane half-swap
    float rs = 0.f;
    bf16x8 pa[4];
#pragma unroll
    for (int s4 = 0; s4 < 4; ++s4) {
      const int rb = 8 * (s4 & 1);
      float p[8];
#pragma unroll
      for (int j = 0; j < 8; ++j) {
        float sv = (s4 < 2) ? ((const float*)&s0)[rb + j] : ((const float*)&s1)[rb + j];
        p[j] = fexp2(sv);
      }
      rs += ((p[0] + p[1]) + (p[2] + p[3])) + ((p[4] + p[5]) + (p[6] + p[7]));
      u32 w10 = cvtpk(p[0], p[1]);
      u32 w11 = cvtpk(p[2], p[3]);
      u32 w20 = cvtpk(p[4], p[5]);
      u32 w21 = cvtpk(p[6], p[7]);
      plswap(w10, w20);  // w10 -> [w10.lo, w20.lo]; w20 -> [w10.hi, w20.hi]
      plswap(w11, w21);
      u32x4 af;
      af[0] = w10;
      af[1] = w11;
      af[2] = w20;
      af[3] = w21;
      pa[s4] = *(bf16x8*)&af;  // t-window s4*16
    }
    rs += __shfl_xor(rs, 32, 64);
    l_r += rs;

    // O += P V
    __builtin_amdgcn_s_setprio(1);
#pragma unroll
    for (int s4 = 0; s4 < 4; ++s4) {
      int rowd = lq, c = s4 * 2 + hi;
      bf16x8 vf = *(const bf16x8*)(vl + rowd * 64 + (c ^ (rowd & 7)) * 8);
      o0 = __builtin_amdgcn_mfma_f32_32x32x16_bf16(pa[s4], vf, o0, 0, 0, 0);
    }
#pragma unroll
    for (int s4 = 0; s4 < 4; ++s4) {
      int rowd = 32 + lq, c = s4 * 2 + hi;
      bf16x8 vf = *(const bf16x8*)(vl + rowd * 64 + (c ^ (rowd & 7)) * 8);
      o1 = __builtin_amdgcn_mfma_f32_32x32x16_bf16(pa[s4], vf, o1, 0, 0, 0);
    }
    __builtin_amdgcn_s_setprio(0);
  }

  // write unnormalized partials (D-layout: q(reg r) = (r&3)+8*(r>>2)+4*hi, d-col = lq)
  u16* opb = (kvh == 3) ? Op3 : (Op + (size_t)kvh * 4194304);
#pragma unroll
  for (int r = 0; r < 16; ++r) {
    int qr = (r & 3) + 8 * (r >> 2) + 4 * hi;
    u16* hp = opb + ((size_t)bh * 2048 + qt + qr) * 64;
    hp[lq] = f2bf(o0[r]);
    hp[32 + lq] = f2bf(o1[r]);
  }
  if (hi == 0) Lp[(size_t)kvh * 65536 + (size_t)bh * 2048 + qt + lq] = l_r;
}

// ---------------- combine: Hd = (Op0+Op1+Op2+Op3) / (L0+L1+L2+L3), Op3 in-place ----------------
__global__ __launch_bounds__(256) void combine_kernel(const u16* __restrict__ Op,
                                                      const float* __restrict__ Lp,
                                                      u16* __restrict__ Hd) {
  const int idx = blockIdx.x * 256 + threadIdx.x;  // 524288 threads: row g, d-oct j
  const int g = idx >> 3, j = idx & 7;
  const float fac =
      1.f / (Lp[g] + Lp[65536 + g] + Lp[131072 + g] + Lp[196608 + g]);
  const size_t off = (size_t)g * 64 + j * 8;
  u32x4 v0 = *(const u32x4*)(Op + off);
  u32x4 v1 = *(const u32x4*)(Op + 4194304 + off);
  u32x4 v2 = *(const u32x4*)(Op + 2ull * 4194304 + off);
  u32x4 v3 = *(const u32x4*)(Hd + off);  // Op3 aliases Hd (1:1 read-then-write)
  const u16* p0 = (const u16*)&v0;
  const u16* p1 = (const u16*)&v1;
  const u16* p2 = (const u16*)&v2;
  const u16* p3 = (const u16*)&v3;
  u32x4 outv;
  u16* po = (u16*)&outv;
#pragma unroll
  for (int e = 0; e < 8; ++e)
    po[e] = f2bf((bf2f(p0[e]) + bf2f(p1[e]) + bf2f(p2[e]) + bf2f(p3[e])) * fac);
  *(u32x4*)(Hd + off) = outv;
}

// ---------------- launch ----------------
extern "C" void kernel_launch(void* const* d_in, const int* in_sizes, int n_in,
                              void* d_out, int out_size, void* d_ws, size_t ws_size,
                              hipStream_t stream) {
  const float* Q = (const float*)d_in[0];
  const float* K = (const float*)d_in[1];
  const float* V = (const float*)d_in[2];
  const float* WQ = (const float*)d_in[3];
  const float* WK = (const float*)d_in[4];
  const float* WV = (const float*)d_in[5];
  const float* WO = (const float*)d_in[6];
  float* out = (float*)d_out;

  size_t off = 0;
  char* ws = (char*)d_ws;
  auto nxt = [&](size_t n) { void* p = ws + off; off += (n + 255) & ~(size_t)255; return p; };
  u16* Qb = (u16*)nxt(3ull * 4096 * 1024 * 2);   // Qb,Kb,Vb contiguous (dead after proj GEMM)
  u16* Qi = (u16*)nxt(3ull * 4096 * 1024 * 2);   // Qi,Ki,Vi contiguous
  u16* Vtb = (u16*)nxt(4096ull * 1024 * 2);
  u16* Hd = (u16*)nxt(4096ull * 1024 * 2);
  u16* Wt = (u16*)nxt(3ull * 1048576 * 2);
  u16* Wot = (u16*)nxt(1048576ull * 2);
  float* Lp = (float*)nxt(4ull * 65536 * 4);
  u16* Ki = Qi + 4194304;
  u16* Vi = Qi + 2 * 4194304;
  // attention partials: Op[0..2] alias dead Qb region (3 x 8.4MB = exactly 25.2MB),
  // Op[3] aliases Hd (combined in-place).
  u16* Op = Qb;

  prep_kernel<<<4096, 256, 0, stream>>>(Q, K, V, Qb, Qb + 4194304, Qb + 2 * 4194304);

  transposeW_kernel<<<1024, 256, 0, stream>>>(WQ, WK, WV, WO, Wt, Wot);

  // fused Q/K/V projections: z picks (A, W, C) triple
  gemm_kernel<1><<<dim3(32, 8, 3), 256, 0, stream>>>(Qb, Wt, Qi);

  transposeV_kernel<<<dim3(32, 32), 256, 0, stream>>>(Vi, Vtb);

  attn_kernel<<<2048, 256, 0, stream>>>(Qi, Ki, Vtb, Op, Hd, Lp);

  combine_kernel<<<2048, 256, 0, stream>>>(Op, Lp, Hd);

  gemm_kernel<0><<<dim3(32, 8, 1), 256, 0, stream>>>(Hd, Wot, out);
}

// Round 15
// 132.941 us; speedup vs baseline: 1.1592x; 1.0311x over previous
//
#include <hip/hip_runtime.h>
#include <hip/hip_bf16.h>
#include <stdint.h>

typedef unsigned short u16;
typedef unsigned int u32;
typedef __attribute__((ext_vector_type(4))) float f32x4;
typedef __attribute__((ext_vector_type(16))) float f32x16;
typedef __attribute__((ext_vector_type(8))) short bf16x8;
typedef __attribute__((ext_vector_type(4))) unsigned int u32x4;
typedef __attribute__((ext_vector_type(2))) unsigned int u32x2;

#define DEV __device__ __forceinline__

DEV u16 f2bf(float f) {
  union { float f; uint32_t u; } v; v.f = f;
  uint32_t u = v.u;
  return (u16)((u + 0x7fffu + ((u >> 16) & 1u)) >> 16);
}
DEV float bf2f(u16 h) {
  union { uint32_t u; float f; } v; v.u = ((uint32_t)h) << 16;
  return v.f;
}

DEV u32 cvtpk(float a, float b) {  // D.lo = bf16(a), D.hi = bf16(b), RNE
  u32 r;
  asm("v_cvt_pk_bf16_f32 %0, %1, %2" : "=v"(r) : "v"(a), "v"(b));
  return r;
}

// v_permlane32_swap_b32 a, b: a' = [a.lo32lanes, b.lo32lanes], b' = [a.hi, b.hi]
DEV void plswap(u32& a, u32& b) {
  asm("v_permlane32_swap_b32 %0, %1" : "+v"(a), "+v"(b));
}

// raw 2^x — single quarter-rate trans op (libm exp2f carries range/denorm guards)
DEV float fexp2(float x) {
  float r;
  asm("v_exp_f32 %0, %1" : "=v"(r) : "v"(x));
  return r;
}

DEV void gload_lds16(const u16* g, u16* l) {
  __builtin_amdgcn_global_load_lds(
      (const __attribute__((address_space(1))) void*)g,
      (__attribute__((address_space(3))) void*)l, 16, 0, 0);
}

// ---------------- prep: fp32 -> bf16 for Q/K/V (coalesced float4) ----------------
__global__ __launch_bounds__(256) void prep_kernel(
    const float* __restrict__ Q, const float* __restrict__ K, const float* __restrict__ V,
    u16* __restrict__ Qb, u16* __restrict__ Kb, u16* __restrict__ Vb) {
  const int i = blockIdx.x * 256 + threadIdx.x;  // 1,048,576 threads
#pragma unroll
  for (int it = 0; it < 3; ++it) {
    int idx = it * 1048576 + i;
    int which = idx >> 20, j = idx & 1048575;
    const float* src = which == 0 ? Q : (which == 1 ? K : V);
    u16* dst = which == 0 ? Qb : (which == 1 ? Kb : Vb);
    float4 v = ((const float4*)src)[j];
    u32x2 pk;
    pk[0] = (u32)f2bf(v.x) | ((u32)f2bf(v.y) << 16);
    pk[1] = (u32)f2bf(v.z) | ((u32)f2bf(v.w) << 16);
    *(u32x2*)(dst + (size_t)j * 4) = pk;
  }
}

// ---------------- tiled weight transpose (coalesced both sides) ----------------
// blocks 0..767:  Wt[p][(h*64+k)][d] = W_p[h][d][k]   (64x64 tile (p,h,dt))
// blocks 768..1023: Wot[c][k] = WO[k][c]              (64x64 tile (kt,ct))
__global__ __launch_bounds__(256) void transposeW_kernel(
    const float* __restrict__ WQ, const float* __restrict__ WK, const float* __restrict__ WV,
    const float* __restrict__ WO, u16* __restrict__ Wt, u16* __restrict__ Wot) {
  __shared__ __align__(16) u16 tl[64][72];
  const int tid = threadIdx.x;
  const int bid = blockIdx.x;
  const float* src;
  u16* dst;
  int rstride;
  if (bid < 768) {
    int p = bid >> 8, rest = bid & 255;
    int h = rest >> 4, dt = rest & 15;
    const float* W = p == 0 ? WQ : (p == 1 ? WK : WV);
    src = W + (size_t)(h * 1024 + dt * 64) * 64;       // rows = d (stride 64 floats)
    dst = Wt + (size_t)p * 1048576 + (size_t)h * 64 * 1024 + dt * 64;  // rows = k
    rstride = 64;
  } else {
    int idx2 = bid - 768;
    int kt = idx2 >> 4, ct = idx2 & 15;
    src = WO + (size_t)kt * 64 * 1024 + ct * 64;       // rows = k (stride 1024 floats)
    dst = Wot + (size_t)ct * 64 * 1024 + kt * 64;      // rows = c
    rstride = 1024;
  }
  // load 64x64 f32 tile -> bf16 LDS (reads coalesced along source rows)
#pragma unroll
  for (int i = 0; i < 2; ++i) {
    int idx = i * 256 + tid;
    int row = idx >> 3, c8 = idx & 7;
    const float* sp = src + (size_t)row * rstride + c8 * 8;
    float4 a = *(const float4*)sp;
    float4 b = *(const float4*)(sp + 4);
    u32x4 pk;
    pk[0] = (u32)f2bf(a.x) | ((u32)f2bf(a.y) << 16);
    pk[1] = (u32)f2bf(a.z) | ((u32)f2bf(a.w) << 16);
    pk[2] = (u32)f2bf(b.x) | ((u32)f2bf(b.y) << 16);
    pk[3] = (u32)f2bf(b.z) | ((u32)f2bf(b.w) << 16);
    *(u32x4*)&tl[row][c8 * 8] = pk;
  }
  __syncthreads();
  // write transposed (16B vector stores, coalesced)
#pragma unroll
  for (int i = 0; i < 2; ++i) {
    int idx = i * 256 + tid;
    int row2 = idx >> 3, s8 = idx & 7;
    u32x4 outv;
    u16* tp = (u16*)&outv;
#pragma unroll
    for (int j = 0; j < 8; ++j) tp[j] = tl[s8 * 8 + j][row2];
    *(u32x4*)(dst + (size_t)row2 * 1024 + s8 * 8) = outv;
  }
}

// ---------------- GEMM: C[4096][1024] = A[4096][1024] * Bt^T, z-batched ----------------
// LB(256,3): 3 blocks/CU co-resident (768-block proj launch fully resident) so barrier
// drains overlap across blocks. VGPR cap 170 — est. live ~130, no spill expected.
template <int OUT_BF16>
__global__ __launch_bounds__(256, 3) void gemm_kernel(const u16* __restrict__ A,
                                                      const u16* __restrict__ Bt,
                                                      void* __restrict__ Cout) {
  __shared__ __align__(16) u16 Alds[128 * 64];
  __shared__ __align__(16) u16 Blds[128 * 64];
  const size_t zo = blockIdx.z;
  A += zo * 4194304;
  Bt += zo * 1048576;
  const int tid = threadIdx.x;
  const int l = tid & 63, w = tid >> 6;
  const int wm = w >> 1, wn = w & 1;
  const int d = blockIdx.x + 32 * blockIdx.y;
  const int orig = (d & 7) * 32 + (d >> 3);
  const int tileM = (orig & 31) * 128, tileN = (orig >> 5) * 128;
  const int lr = l >> 3, lch = l & 7;

  f32x4 acc[4][4] = {};

  for (int kt = 0; kt < 16; ++kt) {
    const int k0 = kt * 64;
#pragma unroll
    for (int i = 0; i < 4; ++i) {
      int r = i * 32 + w * 8 + lr;
      int sch = lch ^ (r & 7);
      gload_lds16(A + (size_t)(tileM + r) * 1024 + k0 + sch * 8, Alds + i * 2048 + w * 512);
      gload_lds16(Bt + (size_t)(tileN + r) * 1024 + k0 + sch * 8, Blds + i * 2048 + w * 512);
    }
    __syncthreads();
    bf16x8 af[4][2], bfr[4][2];
#pragma unroll
    for (int m = 0; m < 4; ++m) {
#pragma unroll
      for (int kk = 0; kk < 2; ++kk) {
        int row = wm * 64 + m * 16 + (l & 15);
        int ch = ((l >> 4) + kk * 4) ^ (row & 7);
        af[m][kk] = *(const bf16x8*)(Alds + row * 64 + ch * 8);
        int rowb = wn * 64 + m * 16 + (l & 15);
        int chb = ((l >> 4) + kk * 4) ^ (rowb & 7);
        bfr[m][kk] = *(const bf16x8*)(Blds + rowb * 64 + chb * 8);
      }
    }
#pragma unroll
    for (int m = 0; m < 4; ++m)
#pragma unroll
      for (int n = 0; n < 4; ++n)
#pragma unroll
        for (int kk = 0; kk < 2; ++kk)
          acc[m][n] = __builtin_amdgcn_mfma_f32_16x16x32_bf16(af[m][kk], bfr[n][kk], acc[m][n], 0, 0, 0);
    __syncthreads();
  }
#pragma unroll
  for (int m = 0; m < 4; ++m) {
    int row0 = tileM + wm * 64 + m * 16 + ((l >> 4) << 2);
#pragma unroll
    for (int n = 0; n < 4; ++n) {
      int col = tileN + wn * 64 + n * 16 + (l & 15);
#pragma unroll
      for (int q = 0; q < 4; ++q) {
        if (OUT_BF16)
          ((u16*)Cout)[zo * 4194304 + (size_t)(row0 + q) * 1024 + col] = f2bf(acc[m][n][q]);
        else
          ((float*)Cout)[(size_t)(row0 + q) * 1024 + col] = acc[m][n][q];
      }
    }
  }
}

// ---------------- transpose Vi[4096][1024] -> Vt[(bh*64+dk)][2048] ----------------
__global__ __launch_bounds__(256) void transposeV_kernel(const u16* __restrict__ Vi,
                                                         u16* __restrict__ Vt) {
  __shared__ __align__(16) u16 tl[64][72];
  const int tid = threadIdx.x;
  const int st = blockIdx.x * 64;
  const int bh = blockIdx.y;
  const int b = bh >> 4, h = bh & 15;
#pragma unroll
  for (int i = 0; i < 2; ++i) {
    int idx = i * 256 + tid;
    int s = idx >> 3, ch = idx & 7;
    const u16* src = Vi + (size_t)(b * 2048 + st + s) * 1024 + h * 64 + ch * 8;
    u32x2 a = *(const u32x2*)src;
    u32x2 bb = *(const u32x2*)(src + 4);
    *(u32x2*)&tl[s][ch * 8] = a;
    *(u32x2*)&tl[s][ch * 8 + 4] = bb;
  }
  __syncthreads();
#pragma unroll
  for (int i = 0; i < 2; ++i) {
    int idx = i * 256 + tid;
    int dk = idx >> 3, ch = idx & 7;
    u32x4 outv;
    u16* tp = (u16*)&outv;
#pragma unroll
    for (int j = 0; j < 8; ++j) tp[j] = tl[ch * 8 + j][dk];
    *(u32x4*)(Vt + ((size_t)bh * 64 + dk) * 2048 + st + ch * 8) = outv;
  }
}

// ---------------- flash attention: LDS-staged K/V + in-register softmax ----------------
// r13-verified config: kv-split 2 (grid 1024, 16 tiles/wave) — r14's split-4 regressed
// (2x partial write traffic, no occupancy gain). fexp2 + plswap + VALU row-sum.
__global__ __launch_bounds__(256, 4) void attn_kernel(const u16* __restrict__ Qi,
                                                      const u16* __restrict__ Ki,
                                                      const u16* __restrict__ Vt,
                                                      u16* __restrict__ Op,
                                                      float* __restrict__ Lp) {
  __shared__ __align__(16) u16 Kl[2][4096];
  __shared__ __align__(16) u16 Vl[2][4096];
  const int tid = threadIdx.x;
  const int l = tid & 63, w = tid >> 6;
  const int lq = l & 31, hi = l >> 5;
  const int lr = l >> 3, lch = l & 7;
  // bijective XCD chunk swizzle: 1024 blocks, XCD dd%8 gets 128 contiguous (=4 bh)
  const int dd = blockIdx.x;
  const int orig = (dd & 7) * 128 + (dd >> 3);
  const int bh = orig >> 5;
  const int rem = orig & 31;
  const int qb = rem >> 1, kvh = rem & 1;
  const int b = bh >> 4, h = bh & 15;
  const int qt = qb * 128 + w * 32;
  const int tb = kvh * 1024;

  const u16* Kbase = Ki + (size_t)b * 2048 * 1024 + h * 64;
  const u16* Vbase = Vt + (size_t)bh * 64 * 2048;

  // Q B-frags (col q = lq, k = s*16 + hi*8 + j), prescaled by log2(e)/8 (exp2 domain)
  bf16x8 qf[4];
  {
    const u16* qp = Qi + (size_t)(b * 2048 + qt + lq) * 1024 + h * 64 + hi * 8;
#pragma unroll
    for (int s = 0; s < 4; ++s) {
      u32x4 t4 = *(const u32x4*)(qp + s * 16);
      u16* tp = (u16*)&t4;
#pragma unroll
      for (int j = 0; j < 8; ++j) tp[j] = f2bf(bf2f(tp[j]) * 0.1803368867f);
      qf[s] = *(bf16x8*)&t4;
    }
  }

  f32x16 o0 = {}, o1 = {};
  float l_r = 0.f;

  // stage tile `t` into buffer `bb`: K [64 t-rows][64 k], V^T [64 d-rows][64 t]
  auto STAGE = [&](int bb, int t) {
#pragma unroll
    for (int i = 0; i < 2; ++i) {
      int r = i * 32 + w * 8 + lr;
      int sch = lch ^ (r & 7);
      gload_lds16(Kbase + (size_t)(tb + t * 64 + r) * 1024 + sch * 8,
                  Kl[bb] + i * 2048 + w * 512);
      gload_lds16(Vbase + (size_t)r * 2048 + tb + t * 64 + sch * 8,
                  Vl[bb] + i * 2048 + w * 512);
    }
  };

  STAGE(0, 0);

#pragma unroll 2
  for (int tile = 0; tile < 16; ++tile) {
    const int cur = tile & 1;
    __syncthreads();  // compiler drains vmcnt: staged tile `cur` ready
    if (tile + 1 < 16) STAGE(cur ^ 1, tile + 1);
    const u16* kl = Kl[cur];
    const u16* vl = Vl[cur];

    // S^T = K Q^T: two 32-t halves
    f32x16 s0 = {}, s1 = {};
    __builtin_amdgcn_s_setprio(1);
#pragma unroll
    for (int s = 0; s < 4; ++s) {
      int row = lq, c = s * 2 + hi;
      bf16x8 kf = *(const bf16x8*)(kl + row * 64 + (c ^ (row & 7)) * 8);
      s0 = __builtin_amdgcn_mfma_f32_32x32x16_bf16(kf, qf[s], s0, 0, 0, 0);
    }
#pragma unroll
    for (int s = 0; s < 4; ++s) {
      int row = 32 + lq, c = s * 2 + hi;
      bf16x8 kf = *(const bf16x8*)(kl + row * 64 + (c ^ (row & 7)) * 8);
      s1 = __builtin_amdgcn_mfma_f32_32x32x16_bf16(kf, qf[s], s1, 0, 0, 0);
    }
    __builtin_amdgcn_s_setprio(0);

    // P = exp2(S) via raw v_exp_f32; row-sum tree on VALU; pack; permlane half-swap
    float rs = 0.f;
    bf16x8 pa[4];
#pragma unroll
    for (int s4 = 0; s4 < 4; ++s4) {
      const int rb = 8 * (s4 & 1);
      float p[8];
#pragma unroll
      for (int j = 0; j < 8; ++j) {
        float sv = (s4 < 2) ? ((const float*)&s0)[rb + j] : ((const float*)&s1)[rb + j];
        p[j] = fexp2(sv);
      }
      rs += ((p[0] + p[1]) + (p[2] + p[3])) + ((p[4] + p[5]) + (p[6] + p[7]));
      u32 w10 = cvtpk(p[0], p[1]);
      u32 w11 = cvtpk(p[2], p[3]);
      u32 w20 = cvtpk(p[4], p[5]);
      u32 w21 = cvtpk(p[6], p[7]);
      plswap(w10, w20);  // w10 -> [w10.lo, w20.lo]; w20 -> [w10.hi, w20.hi]
      plswap(w11, w21);
      u32x4 af;
      af[0] = w10;
      af[1] = w11;
      af[2] = w20;
      af[3] = w21;
      pa[s4] = *(bf16x8*)&af;  // t-window s4*16
    }
    rs += __shfl_xor(rs, 32, 64);
    l_r += rs;

    // O += P V
    __builtin_amdgcn_s_setprio(1);
#pragma unroll
    for (int s4 = 0; s4 < 4; ++s4) {
      int rowd = lq, c = s4 * 2 + hi;
      bf16x8 vf = *(const bf16x8*)(vl + rowd * 64 + (c ^ (rowd & 7)) * 8);
      o0 = __builtin_amdgcn_mfma_f32_32x32x16_bf16(pa[s4], vf, o0, 0, 0, 0);
    }
#pragma unroll
    for (int s4 = 0; s4 < 4; ++s4) {
      int rowd = 32 + lq, c = s4 * 2 + hi;
      bf16x8 vf = *(const bf16x8*)(vl + rowd * 64 + (c ^ (rowd & 7)) * 8);
      o1 = __builtin_amdgcn_mfma_f32_32x32x16_bf16(pa[s4], vf, o1, 0, 0, 0);
    }
    __builtin_amdgcn_s_setprio(0);
  }

  // write unnormalized partials (D-layout: q(reg r) = (r&3)+8*(r>>2)+4*hi, d-col = lq)
#pragma unroll
  for (int r = 0; r < 16; ++r) {
    int qr = (r & 3) + 8 * (r >> 2) + 4 * hi;
    u16* hp = Op + (size_t)kvh * 4194304 + ((size_t)bh * 2048 + qt + qr) * 64;
    hp[lq] = f2bf(o0[r]);
    hp[32 + lq] = f2bf(o1[r]);
  }
  if (hi == 0) Lp[(size_t)kvh * 65536 + (size_t)bh * 2048 + qt + lq] = l_r;
}

// ---------------- combine: Hd = (Op0 + Op1) / (L0 + L1) ----------------
__global__ __launch_bounds__(256) void combine_kernel(const u16* __restrict__ Op,
                                                      const float* __restrict__ Lp,
                                                      u16* __restrict__ Hd) {
  const int idx = blockIdx.x * 256 + threadIdx.x;  // 524288 threads: row g, d-oct j
  const int g = idx >> 3, j = idx & 7;
  const float fac = 1.f / (Lp[g] + Lp[65536 + g]);
  const size_t off = (size_t)g * 64 + j * 8;
  u32x4 va = *(const u32x4*)(Op + off);
  u32x4 vb = *(const u32x4*)(Op + 4194304 + off);
  const u16* pa = (const u16*)&va;
  const u16* pb = (const u16*)&vb;
  u32x4 outv;
  u16* po = (u16*)&outv;
#pragma unroll
  for (int e = 0; e < 8; ++e) po[e] = f2bf((bf2f(pa[e]) + bf2f(pb[e])) * fac);
  *(u32x4*)(Hd + off) = outv;
}

// ---------------- launch ----------------
extern "C" void kernel_launch(void* const* d_in, const int* in_sizes, int n_in,
                              void* d_out, int out_size, void* d_ws, size_t ws_size,
                              hipStream_t stream) {
  const float* Q = (const float*)d_in[0];
  const float* K = (const float*)d_in[1];
  const float* V = (const float*)d_in[2];
  const float* WQ = (const float*)d_in[3];
  const float* WK = (const float*)d_in[4];
  const float* WV = (const float*)d_in[5];
  const float* WO = (const float*)d_in[6];
  float* out = (float*)d_out;

  size_t off = 0;
  char* ws = (char*)d_ws;
  auto nxt = [&](size_t n) { void* p = ws + off; off += (n + 255) & ~(size_t)255; return p; };
  u16* Qb = (u16*)nxt(3ull * 4096 * 1024 * 2);   // Qb,Kb,Vb contiguous (dead after proj GEMM)
  u16* Qi = (u16*)nxt(3ull * 4096 * 1024 * 2);   // Qi,Ki,Vi contiguous
  u16* Vtb = (u16*)nxt(4096ull * 1024 * 2);
  u16* Hd = (u16*)nxt(4096ull * 1024 * 2);
  u16* Wt = (u16*)nxt(3ull * 1048576 * 2);
  u16* Wot = (u16*)nxt(1048576ull * 2);
  float* Lp = (float*)nxt(2ull * 65536 * 4);
  u16* Ki = Qi + 4194304;
  u16* Vi = Qi + 2 * 4194304;
  // attention partials: Op[0..1] alias dead Qb region (16.8MB < 25.2MB)
  u16* Op = Qb;

  prep_kernel<<<4096, 256, 0, stream>>>(Q, K, V, Qb, Qb + 4194304, Qb + 2 * 4194304);

  transposeW_kernel<<<1024, 256, 0, stream>>>(WQ, WK, WV, WO, Wt, Wot);

  // fused Q/K/V projections: z picks (A, W, C) triple
  gemm_kernel<1><<<dim3(32, 8, 3), 256, 0, stream>>>(Qb, Wt, Qi);

  transposeV_kernel<<<dim3(32, 32), 256, 0, stream>>>(Vi, Vtb);

  attn_kernel<<<1024, 256, 0, stream>>>(Qi, Ki, Vtb, Op, Lp);

  combine_kernel<<<2048, 256, 0, stream>>>(Op, Lp, Hd);

  gemm_kernel<0><<<dim3(32, 8, 1), 256, 0, stream>>>(Hd, Wot, out);
}